// Round 6
// baseline (143.432 us; speedup 1.0000x reference)
//
#include <hip/hip_runtime.h>

#define N_FEAT 2048
#define ORDER 8
#define BATCH 8192
#define BLOCK 256
#define WPB 4           // waves per block; one wave owns one batch row

typedef float v4f __attribute__((ext_vector_type(4)));

__device__ __forceinline__ float dot4(v4f a, v4f b) {
    return a.x * b.x + a.y * b.y + a.z * b.z + a.w * b.w;
}

// Prep kernel (1 block): normalize the 8 reflection vectors into vn AND build
// the compact-WY T factor: H0..H7 = I - Vn^T T Vn, T upper-tri, diag=2,
// T[j][k] = -2 * sum_{m=j}^{k-1} T[j][m] * G[m][k],  G = Vn Vn^T.
__global__ __launch_bounds__(BLOCK) void prep_kernel(
    const float* __restrict__ v, float* __restrict__ vn, float* __restrict__ Tout) {
    const int tid = threadIdx.x;
    const int lane = tid & 63, wid = tid >> 6;

    v4f a0[ORDER], a1[ORDER];
    #pragma unroll
    for (int i = 0; i < ORDER; ++i) {
        a0[i] = *(const v4f*)(v + (size_t)i * N_FEAT + tid * 4);
        a1[i] = *(const v4f*)(v + (size_t)i * N_FEAT + 1024 + tid * 4);
    }
    // norms + 28 pair dots of RAW vectors (rescale later by inv_i*inv_j)
    float ss[ORDER];
    #pragma unroll
    for (int i = 0; i < ORDER; ++i)
        ss[i] = dot4(a0[i], a0[i]) + dot4(a1[i], a1[i]);
    float pr[28];
    #pragma unroll
    for (int i = 0, c = 0; i < ORDER; ++i)
        #pragma unroll
        for (int j = i + 1; j < ORDER; ++j, ++c)
            pr[c] = dot4(a0[i], a0[j]) + dot4(a1[i], a1[j]);

    #pragma unroll
    for (int o = 32; o > 0; o >>= 1) {
        #pragma unroll
        for (int i = 0; i < ORDER; ++i) ss[i] += __shfl_down(ss[i], o, 64);
        #pragma unroll
        for (int c = 0; c < 28; ++c) pr[c] += __shfl_down(pr[c], o, 64);
    }
    __shared__ float rss[4][ORDER];
    __shared__ float rpr[4][28];
    if (lane == 0) {
        #pragma unroll
        for (int i = 0; i < ORDER; ++i) rss[wid][i] = ss[i];
        #pragma unroll
        for (int c = 0; c < 28; ++c) rpr[wid][c] = pr[c];
    }
    __syncthreads();

    float inv[ORDER];
    #pragma unroll
    for (int i = 0; i < ORDER; ++i) {
        inv[i] = 1.0f / sqrtf(rss[0][i] + rss[1][i] + rss[2][i] + rss[3][i]);
        *(v4f*)(vn + (size_t)i * N_FEAT + tid * 4) = a0[i] * inv[i];
        *(v4f*)(vn + (size_t)i * N_FEAT + 1024 + tid * 4) = a1[i] * inv[i];
    }

    if (tid == 0) {
        float G[ORDER][ORDER];
        for (int i = 0, c = 0; i < ORDER; ++i) {
            G[i][i] = 1.0f;
            for (int j = i + 1; j < ORDER; ++j, ++c) {
                float g = (rpr[0][c] + rpr[1][c] + rpr[2][c] + rpr[3][c]) * inv[i] * inv[j];
                G[i][j] = g; G[j][i] = g;
            }
        }
        float T[ORDER][ORDER];
        for (int i = 0; i < ORDER; ++i)
            for (int j = 0; j < ORDER; ++j) T[i][j] = 0.f;
        T[0][0] = 2.0f;
        for (int k = 1; k < ORDER; ++k) {
            for (int j = 0; j < k; ++j) {
                float s = 0.f;
                for (int m = j; m < k; ++m) s += T[j][m] * G[m][k];
                T[j][k] = -2.0f * s;
            }
            T[k][k] = 2.0f;
        }
        for (int i = 0; i < ORDER; ++i)
            for (int j = 0; j < ORDER; ++j) Tout[i * ORDER + j] = T[i][j];
    }
}

// Apply kernel: ONE WAVE PER ROW, compact-WY form -> ONE reduction round.
//   p = z . vn_i (8 independent dots)  [butterfly all-reduce, 8 chains]
//   q = -(p T)                          [per-lane, T via scalar loads]
//   z' = z + sum_j q_j vn_j             [vn re-loaded from L1, stays 8 v4f live]
// Zero LDS, zero barriers.
__global__ __launch_bounds__(BLOCK) void orth_apply_kernel(
    const float* __restrict__ x, const float* __restrict__ vn,
    const float* __restrict__ T, const float* __restrict__ d,
    const float* __restrict__ bias, float* __restrict__ y) {
    const int tid = threadIdx.x;
    const int lane = tid & 63, wid = tid >> 6;
    const int row = blockIdx.x * WPB + wid;
    const size_t base = (size_t)row * N_FEAT;
    const int col = lane * 4;

    v4f z[8];
    #pragma unroll
    for (int c = 0; c < 8; ++c)
        z[c] = *(const v4f*)(x + base + c * 256 + col);

    // Phase 1: partial dots, 4 accumulators each to cut the FMA chain.
    float p[ORDER];
    #pragma unroll
    for (int i = 0; i < ORDER; ++i) {
        const float* vr = vn + (size_t)i * N_FEAT;
        float s0 = 0.f, s1 = 0.f, s2 = 0.f, s3 = 0.f;
        #pragma unroll
        for (int c = 0; c < 8; c += 4) {
            s0 += dot4(z[c + 0], *(const v4f*)(vr + (c + 0) * 256 + col));
            s1 += dot4(z[c + 1], *(const v4f*)(vr + (c + 1) * 256 + col));
            s2 += dot4(z[c + 2], *(const v4f*)(vr + (c + 2) * 256 + col));
            s3 += dot4(z[c + 3], *(const v4f*)(vr + (c + 3) * 256 + col));
        }
        p[i] = (s0 + s1) + (s2 + s3);
    }

    // Phase 2: ONE butterfly round, 8 independent chains pipeline the DS unit.
    #pragma unroll
    for (int o = 1; o < 64; o <<= 1)
        #pragma unroll
        for (int i = 0; i < ORDER; ++i) p[i] += __shfl_xor(p[i], o, 64);

    // Phase 3: q = -(p T), T upper-triangular, uniform scalar loads.
    float q[ORDER];
    #pragma unroll
    for (int j = 0; j < ORDER; ++j) {
        float s = 0.f;
        #pragma unroll
        for (int i = 0; i <= j; ++i) s += p[i] * T[i * ORDER + j];
        q[j] = -s;
    }

    // Phase 4: z' = z + sum_j q_j * vn_j (vn chunks re-loaded, L1-hot).
    #pragma unroll
    for (int j = 0; j < ORDER; ++j) {
        const float* vr = vn + (size_t)j * N_FEAT;
        const float qj = q[j];
        #pragma unroll
        for (int c = 0; c < 8; ++c)
            z[c] += qj * *(const v4f*)(vr + c * 256 + col);
    }

    #pragma unroll
    for (int c = 0; c < 8; ++c) {
        const v4f dd = *(const v4f*)(d + c * 256 + col);
        const v4f bb = *(const v4f*)(bias + c * 256 + col);
        v4f o = z[c] * dd + bb;
        __builtin_nontemporal_store(o, (v4f*)(y + base + c * 256 + col));
    }
}

extern "C" void kernel_launch(void* const* d_in, const int* in_sizes, int n_in,
                              void* d_out, int out_size, void* d_ws, size_t ws_size,
                              hipStream_t stream) {
    const float* x    = (const float*)d_in[0];  // [8192, 2048]
    const float* v    = (const float*)d_in[1];  // [8, 2048]
    const float* d    = (const float*)d_in[2];  // [2048]
    const float* bias = (const float*)d_in[3];  // [2048]
    float* y  = (float*)d_out;                  // [8192, 2048]
    float* vn = (float*)d_ws;                   // [8, 2048]
    float* T  = vn + ORDER * N_FEAT;            // [8, 8]

    prep_kernel<<<1, BLOCK, 0, stream>>>(v, vn, T);
    orth_apply_kernel<<<BATCH / WPB, BLOCK, 0, stream>>>(x, vn, T, d, bias, y);
}

// Round 7
// 129.649 us; speedup vs baseline: 1.1063x; 1.1063x over previous
//
#include <hip/hip_runtime.h>

#define N_FEAT 2048
#define ORDER 8
#define BATCH 8192
#define BLOCK 256
#define ROWS 8          // batch rows per block (shares each vn fragment 8x)

typedef float v4f __attribute__((ext_vector_type(4)));

__device__ __forceinline__ float dot4(v4f a, v4f b) {
    return a.x * b.x + a.y * b.y + a.z * b.z + a.w * b.w;
}

// Prep kernel (1 block): normalize the 8 reflection vectors into ws.
__global__ __launch_bounds__(BLOCK) void prep_kernel(
    const float* __restrict__ v, float* __restrict__ vn) {
    const int tid = threadIdx.x;
    const int lane = tid & 63, wid = tid >> 6;

    v4f a0[ORDER], a1[ORDER];
    #pragma unroll
    for (int i = 0; i < ORDER; ++i) {
        a0[i] = *(const v4f*)(v + (size_t)i * N_FEAT + tid * 4);
        a1[i] = *(const v4f*)(v + (size_t)i * N_FEAT + 1024 + tid * 4);
    }
    float ss[ORDER];
    #pragma unroll
    for (int i = 0; i < ORDER; ++i)
        ss[i] = dot4(a0[i], a0[i]) + dot4(a1[i], a1[i]);
    #pragma unroll
    for (int o = 32; o > 0; o >>= 1)
        #pragma unroll
        for (int i = 0; i < ORDER; ++i) ss[i] += __shfl_down(ss[i], o, 64);

    __shared__ float red[4][ORDER];
    if (lane == 0) {
        #pragma unroll
        for (int i = 0; i < ORDER; ++i) red[wid][i] = ss[i];
    }
    __syncthreads();
    #pragma unroll
    for (int i = 0; i < ORDER; ++i) {
        const float inv = 1.0f / sqrtf(red[0][i] + red[1][i] + red[2][i] + red[3][i]);
        *(v4f*)(vn + (size_t)i * N_FEAT + tid * 4) = a0[i] * inv;
        *(v4f*)(vn + (size_t)i * N_FEAT + 1024 + tid * 4) = a1[i] * inv;
    }
}

// Apply kernel: ROWS=8 batch rows per block. Serialized reflections (8 iters):
// each iteration loads ONE vn fragment (2 v4f/thread) shared by 8 rows of
// dot + axpy, 8 independent butterfly chains, one barrier (double-buffered
// LDS slots). vn L1-side traffic: 8 KB/row (vs 16 at ROWS=4, 64 at ROWS=1).
__global__ __launch_bounds__(BLOCK) void orth_apply_kernel(
    const float* __restrict__ x, const float* __restrict__ vn,
    const float* __restrict__ d, const float* __restrict__ bias,
    float* __restrict__ y) {
    const int tid = threadIdx.x;
    const int lane = tid & 63, wid = tid >> 6;
    const size_t base = (size_t)blockIdx.x * ROWS * N_FEAT;
    const int c0 = tid * 4;          // columns [c0, c0+3]
    const int c1 = 1024 + tid * 4;   // columns [c1, c1+3]

    // 16 independent 16B x-loads in flight per thread.
    v4f z0[ROWS], z1[ROWS];
    #pragma unroll
    for (int r = 0; r < ROWS; ++r) {
        z0[r] = *(const v4f*)(x + base + (size_t)r * N_FEAT + c0);
        z1[r] = *(const v4f*)(x + base + (size_t)r * N_FEAT + c1);
    }

    __shared__ float red[2][4][ROWS];

    #pragma unroll
    for (int i = 0; i < ORDER; ++i) {
        const float* vr = vn + (size_t)i * N_FEAT;
        const v4f a0 = *(const v4f*)(vr + c0);
        const v4f a1 = *(const v4f*)(vr + c1);

        float p[ROWS];
        #pragma unroll
        for (int r = 0; r < ROWS; ++r)
            p[r] = dot4(z0[r], a0) + dot4(z1[r], a1);
        #pragma unroll
        for (int o = 32; o > 0; o >>= 1)
            #pragma unroll
            for (int r = 0; r < ROWS; ++r) p[r] += __shfl_down(p[r], o, 64);

        const int buf = i & 1;
        if (lane == 0) {
            #pragma unroll
            for (int r = 0; r < ROWS; ++r) red[buf][wid][r] = p[r];
        }
        __syncthreads();   // one barrier/iter; buffers alternate so no 2nd sync

        #pragma unroll
        for (int r = 0; r < ROWS; ++r) {
            const float s = -2.0f * (red[buf][0][r] + red[buf][1][r] +
                                     red[buf][2][r] + red[buf][3][r]);
            z0[r] += s * a0;
            z1[r] += s * a1;
        }
    }

    const v4f d0 = *(const v4f*)(d + c0);
    const v4f d1 = *(const v4f*)(d + c1);
    const v4f b0 = *(const v4f*)(bias + c0);
    const v4f b1 = *(const v4f*)(bias + c1);

    #pragma unroll
    for (int r = 0; r < ROWS; ++r) {
        v4f o0 = z0[r] * d0 + b0;
        v4f o1 = z1[r] * d1 + b1;
        __builtin_nontemporal_store(o0, (v4f*)(y + base + (size_t)r * N_FEAT + c0));
        __builtin_nontemporal_store(o1, (v4f*)(y + base + (size_t)r * N_FEAT + c1));
    }
}

extern "C" void kernel_launch(void* const* d_in, const int* in_sizes, int n_in,
                              void* d_out, int out_size, void* d_ws, size_t ws_size,
                              hipStream_t stream) {
    const float* x    = (const float*)d_in[0];  // [8192, 2048]
    const float* v    = (const float*)d_in[1];  // [8, 2048]
    const float* d    = (const float*)d_in[2];  // [2048]
    const float* bias = (const float*)d_in[3];  // [2048]
    float* y  = (float*)d_out;                  // [8192, 2048]
    float* vn = (float*)d_ws;                   // [8, 2048]

    prep_kernel<<<1, BLOCK, 0, stream>>>(v, vn);
    orth_apply_kernel<<<BATCH / ROWS, BLOCK, 0, stream>>>(x, vn, d, bias, y);
}